// Round 1
// baseline (916.164 us; speedup 1.0000x reference)
//
#include <hip/hip_runtime.h>
#include <hip/hip_bf16.h>

typedef unsigned short u16;
typedef __attribute__((ext_vector_type(8))) __bf16 bf16x8;
typedef __attribute__((ext_vector_type(4))) float f32x4;

#define NT 50000
#define DIM 128
#define NEDGE 1600000
#define EB 128
#define NBLK 12500   // NEDGE / EB
#define MSGGRID 256

__device__ __forceinline__ u16 f2bf(float f) {
  unsigned x = __float_as_uint(f);
  x += 0x7fffu + ((x >> 16) & 1u);
  return (u16)(x >> 16);
}

// swizzled element index into a [128][128] bf16 LDS tile (G4 XOR swizzle)
__device__ __forceinline__ int swz(int row, int col) {
  return (row << 7) + (col ^ ((row & 7) << 3));
}

__device__ __forceinline__ void atomAddF32(float* p, float v) {
#if defined(__has_builtin)
#if __has_builtin(__builtin_amdgcn_global_atomic_fadd_f32)
  __builtin_amdgcn_global_atomic_fadd_f32((__attribute__((address_space(1))) float*)p, v);
  return;
#endif
#endif
  atomicAdd(p, v);
}

// ---- prep: W1t / W2t as bf16, pre-swizzled so linear LDS copy == swizzled layout
__global__ void prep_w(const float* __restrict__ W1, const float* __restrict__ W2,
                       u16* __restrict__ wsw) {
  int t = blockIdx.x * 256 + threadIdx.x;   // 0..32767
  int m = t >> 14;
  int p = t & 16383;
  int row = p >> 7;          // n (output feature)
  int colq = p & 127;        // swizzled k slot
  int k = colq ^ ((row & 7) << 3);
  const float* W = m ? W2 : W1;
  wsw[t] = f2bf(W[k * 128 + row]);   // W^T[n][k] = W[k][n]
}

__global__ void copy_h(const float4* __restrict__ H, float4* __restrict__ out) {
  int t = blockIdx.x * 256 + threadIdx.x;
  out[t] = H[t];
}

__launch_bounds__(256, 1)
__global__ void msg_kernel(const float* __restrict__ H,
                           const int* __restrict__ ei,
                           const float* __restrict__ ea,
                           const float* __restrict__ W1,
                           const float* __restrict__ b1,
                           const float* __restrict__ b2,
                           const u16* __restrict__ wsw,
                           float* __restrict__ out) {
  __shared__ __align__(16) u16 lw1[16384];
  __shared__ __align__(16) u16 lw2[16384];
  __shared__ __align__(16) u16 lhj[16384];
  __shared__ __align__(16) u16 lh[16384];
  __shared__ __align__(16) float lep[5][128];   // b1, W1[128..130], b2
  __shared__ __align__(16) float lea[128][4];
  __shared__ int lsrc[128];
  __shared__ int ldst[128];

  const int tid = threadIdx.x;
  const int wv = tid >> 6;
  const int lane = tid & 63;
  const int l15 = lane & 15;
  const int l4 = lane >> 4;
  const int ebase = wv * 32;

  // ---- one-time staging: W (pre-swizzled bf16) + epilogue constants ----
  {
    const int4* g = (const int4*)wsw;
    int4* d1 = (int4*)lw1;
    int4* d2 = (int4*)lw2;
#pragma unroll
    for (int i = 0; i < 8; ++i) { int c = tid + i * 256; d1[c] = g[c]; }
#pragma unroll
    for (int i = 0; i < 8; ++i) { int c = tid + i * 256; d2[c] = g[2048 + c]; }
  }
  if (tid < 128) {
    lep[0][tid] = b1[tid];
    lep[1][tid] = W1[128 * 128 + tid];
    lep[2][tid] = W1[129 * 128 + tid];
    lep[3][tid] = W1[130 * 128 + tid];
    lep[4][tid] = b2[tid];
  }

  for (int ebi = blockIdx.x; ebi < NBLK; ebi += MSGGRID) {
    const int eb = ebi * EB;
    __syncthreads();   // prev iter fully done reading meta/tiles; staging visible on iter 0

    if (tid < 128) {
      int e = eb + tid;
      lsrc[tid] = ei[e];
      ldst[tid] = ei[NEDGE + e];
      lea[tid][0] = ea[e * 3 + 0];
      lea[tid][1] = ea[e * 3 + 1];
      lea[tid][2] = ea[e * 3 + 2];
    }
    __syncthreads();

    // ---- gather Hj rows -> bf16 swizzled LDS ----
    {
      int seg = tid & 15;
      int rbase = tid >> 4;
#pragma unroll
      for (int p = 0; p < 8; ++p) {
        int row = p * 16 + rbase;
        const float* s = H + (long)lsrc[row] * 128 + seg * 8;
        float4 a = *(const float4*)(s);
        float4 c = *(const float4*)(s + 4);
        int4 pk;
        pk.x = f2bf(a.x) | ((int)f2bf(a.y) << 16);
        pk.y = f2bf(a.z) | ((int)f2bf(a.w) << 16);
        pk.z = f2bf(c.x) | ((int)f2bf(c.y) << 16);
        pk.w = f2bf(c.z) | ((int)f2bf(c.w) << 16);
        *(int4*)&lhj[swz(row, seg * 8)] = pk;
      }
    }
    __syncthreads();

    // ---- layer 1 (transposed): D[n][e] = sum_k W1t[n][k] * Hj[e][k] ----
    bf16x8 bfr[2][4];
    float ea0[2], ea1[2], ea2[2];
#pragma unroll
    for (int et = 0; et < 2; ++et) {
      int e = ebase + et * 16 + l15;
#pragma unroll
      for (int ks = 0; ks < 4; ++ks)
        bfr[et][ks] = *(const bf16x8*)&lhj[swz(e, ks * 32 + l4 * 8)];
      ea0[et] = lea[e][0]; ea1[et] = lea[e][1]; ea2[et] = lea[e][2];
    }

#pragma unroll
    for (int nt = 0; nt < 8; ++nt) {
      bf16x8 afr[4];
#pragma unroll
      for (int ks = 0; ks < 4; ++ks)
        afr[ks] = *(const bf16x8*)&lw1[swz(nt * 16 + l15, ks * 32 + l4 * 8)];
      f32x4 acc[2];
      acc[0] = (f32x4){0.f, 0.f, 0.f, 0.f};
      acc[1] = (f32x4){0.f, 0.f, 0.f, 0.f};
#pragma unroll
      for (int et = 0; et < 2; ++et)
#pragma unroll
        for (int ks = 0; ks < 4; ++ks)
          acc[et] = __builtin_amdgcn_mfma_f32_16x16x32_bf16(afr[ks], bfr[et][ks], acc[et], 0, 0, 0);

      f32x4 b1v = *(const f32x4*)&lep[0][nt * 16 + l4 * 4];
      f32x4 w0v = *(const f32x4*)&lep[1][nt * 16 + l4 * 4];
      f32x4 w1v = *(const f32x4*)&lep[2][nt * 16 + l4 * 4];
      f32x4 w2v = *(const f32x4*)&lep[3][nt * 16 + l4 * 4];
#pragma unroll
      for (int et = 0; et < 2; ++et) {
        int e = ebase + et * 16 + l15;
        float hv[4];
#pragma unroll
        for (int r = 0; r < 4; ++r) {
          float v = acc[et][r] + b1v[r] + ea0[et] * w0v[r] + ea1[et] * w1v[r] + ea2[et] * w2v[r];
          hv[r] = 0.5f * v * (1.0f + erff(v * 0.70710678118654752f));
        }
        int2 hp;
        hp.x = f2bf(hv[0]) | ((int)f2bf(hv[1]) << 16);
        hp.y = f2bf(hv[2]) | ((int)f2bf(hv[3]) << 16);
        *(int2*)&lh[swz(e, nt * 16 + l4 * 4)] = hp;
      }
    }
    __syncthreads();

    // ---- layer 2: D[e][n2] = sum_k h[e][k] * W2t[n2][k]  (coalesced atomics) ----
    bf16x8 ha[2][4];
#pragma unroll
    for (int et = 0; et < 2; ++et) {
      int e = ebase + et * 16 + l15;
#pragma unroll
      for (int ks = 0; ks < 4; ++ks)
        ha[et][ks] = *(const bf16x8*)&lh[swz(e, ks * 32 + l4 * 8)];
    }
    int drow[2][4];
#pragma unroll
    for (int et = 0; et < 2; ++et)
#pragma unroll
      for (int r = 0; r < 4; ++r)
        drow[et][r] = ldst[ebase + et * 16 + l4 * 4 + r];

#pragma unroll
    for (int nt = 0; nt < 8; ++nt) {
      bf16x8 bfr2[4];
#pragma unroll
      for (int ks = 0; ks < 4; ++ks)
        bfr2[ks] = *(const bf16x8*)&lw2[swz(nt * 16 + l15, ks * 32 + l4 * 8)];
      float b2v = lep[4][nt * 16 + l15];
#pragma unroll
      for (int et = 0; et < 2; ++et) {
        f32x4 acc = (f32x4){0.f, 0.f, 0.f, 0.f};
#pragma unroll
        for (int ks = 0; ks < 4; ++ks)
          acc = __builtin_amdgcn_mfma_f32_16x16x32_bf16(ha[et][ks], bfr2[ks], acc, 0, 0, 0);
#pragma unroll
        for (int r = 0; r < 4; ++r)
          atomAddF32(out + (long)drow[et][r] * 128 + nt * 16 + l15, acc[r] + b2v);
      }
    }
  }
}

__global__ void ln_rows(float* __restrict__ out, const float* __restrict__ gamma,
                        const float* __restrict__ beta) {
  int wave = threadIdx.x >> 6, lane = threadIdx.x & 63;
  int row = blockIdx.x * 4 + wave;
  float2 v = *(const float2*)(out + (long)row * 128 + lane * 2);
  float s = v.x + v.y;
#pragma unroll
  for (int off = 32; off; off >>= 1) s += __shfl_xor(s, off);
  float mu = s * (1.0f / 128.0f);
  float dx = v.x - mu, dy = v.y - mu;
  float q = dx * dx + dy * dy;
#pragma unroll
  for (int off = 32; off; off >>= 1) q += __shfl_xor(q, off);
  float rs = rsqrtf(q * (1.0f / 128.0f) + 1e-5f);
  float2 g = *(const float2*)(gamma + lane * 2);
  float2 b = *(const float2*)(beta + lane * 2);
  float2 o;
  o.x = dx * rs * g.x + b.x;
  o.y = dy * rs * g.y + b.y;
  *(float2*)(out + (long)row * 128 + lane * 2) = o;
}

extern "C" void kernel_launch(void* const* d_in, const int* in_sizes, int n_in,
                              void* d_out, int out_size, void* d_ws, size_t ws_size,
                              hipStream_t stream) {
  const float* H   = (const float*)d_in[0];
  const int* ei    = (const int*)d_in[1];
  const float* ea  = (const float*)d_in[2];
  const float* W1  = (const float*)d_in[3];
  const float* b1  = (const float*)d_in[4];
  const float* W2  = (const float*)d_in[5];
  const float* b2  = (const float*)d_in[6];
  const float* gam = (const float*)d_in[7];
  const float* bet = (const float*)d_in[8];
  float* out = (float*)d_out;
  u16* wsw = (u16*)d_ws;

  prep_w<<<128, 256, 0, stream>>>(W1, W2, wsw);
  copy_h<<<6250, 256, 0, stream>>>((const float4*)H, (float4*)out);
  msg_kernel<<<MSGGRID, 256, 0, stream>>>(H, ei, ea, W1, b1, b2, wsw, out);
  ln_rows<<<NBLK, 256, 0, stream>>>(out, gam, bet);
}

// Round 2
// 683.924 us; speedup vs baseline: 1.3396x; 1.3396x over previous
//
#include <hip/hip_runtime.h>
#include <hip/hip_bf16.h>

typedef unsigned short u16;
typedef __attribute__((ext_vector_type(8))) __bf16 bf16x8;
typedef __attribute__((ext_vector_type(4))) float f32x4;

#define NT 50000
#define NEDGE 1600000
#define NGRP 100000            // NEDGE / 16
#define GRID 256
#define NWAVE 16
#define TOTWAVE (GRID * NWAVE) // 4096

__device__ __forceinline__ u16 f2bf(float f) {
  unsigned x = __float_as_uint(f);
  x += 0x7fffu + ((x >> 16) & 1u);
  return (u16)(x >> 16);
}

// element index into a [R][128] bf16 LDS tile, 16B-chunk XOR swizzle
__device__ __forceinline__ int swz(int row, int col) {
  return (row << 7) + (col ^ ((row & 7) << 3));
}

// tanh-form GELU: x * sigmoid(2t), t = 0.79788456*(x + 0.044715 x^3)
__device__ __forceinline__ float gelu(float v) {
  float t = v * (0.797884561f + 0.0356774081f * v * v);
  return v * __builtin_amdgcn_rcpf(1.0f + __expf(-2.0f * t));
}

__device__ __forceinline__ void atomAddF32(float* p, float v) {
#if defined(__has_builtin)
#if __has_builtin(__builtin_amdgcn_global_atomic_fadd_f32)
  __builtin_amdgcn_global_atomic_fadd_f32((__attribute__((address_space(1))) float*)p, v);
  return;
#endif
#endif
  atomicAdd(p, v);
}

// W1t / W2t as bf16, pre-swizzled so a linear LDS copy yields the swizzled layout
__global__ void prep_w(const float* __restrict__ W1, const float* __restrict__ W2,
                       u16* __restrict__ wsw) {
  int t = blockIdx.x * 256 + threadIdx.x;   // 0..32767
  int m = t >> 14;
  int p = t & 16383;
  int row = p >> 7;
  int colq = p & 127;
  int k = colq ^ ((row & 7) << 3);
  const float* W = m ? W2 : W1;
  wsw[t] = f2bf(W[k * 128 + row]);          // W^T[n][k] = W[k][n]
}

// H f32 -> bf16 (linear layout; gather swizzle is applied at gather time via source offset)
__global__ void prep_h(const float* __restrict__ H, u16* __restrict__ Hb) {
  int t = blockIdx.x * 256 + threadIdx.x;   // 800000 threads, 8 elems each
  const float4* s = (const float4*)H + (long)t * 2;
  float4 a = s[0], c = s[1];
  int4 pk;
  pk.x = f2bf(a.x) | ((int)f2bf(a.y) << 16);
  pk.y = f2bf(a.z) | ((int)f2bf(a.w) << 16);
  pk.z = f2bf(c.x) | ((int)f2bf(c.y) << 16);
  pk.w = f2bf(c.z) | ((int)f2bf(c.w) << 16);
  ((int4*)Hb)[t] = pk;
}

__global__ void copy_h(const float4* __restrict__ H, float4* __restrict__ out) {
  int t = blockIdx.x * 256 + threadIdx.x;
  out[t] = H[t];
}

template <int BF16H>
__launch_bounds__(1024, 4)
__global__ void msg_kernel(const float* __restrict__ H,
                           const u16* __restrict__ Hb,
                           const int* __restrict__ ei,
                           const float* __restrict__ ea,
                           const float* __restrict__ W1,
                           const float* __restrict__ b1,
                           const float* __restrict__ b2,
                           const u16* __restrict__ wsw,
                           float* __restrict__ out) {
  __shared__ __align__(16) u16 lw1[16384];
  __shared__ __align__(16) u16 lw2[16384];
  __shared__ __align__(16) u16 lhj[NWAVE * 16 * 128];  // per-wave private 16x128 tile
  __shared__ __align__(16) float lep[5][128];          // b1, W1[128..130], b2

  const int tid = threadIdx.x;

  // one-time staging: weights (pre-swizzled bf16) + epilogue constants
  {
    const int4* g = (const int4*)wsw;
    int4* d1 = (int4*)lw1;
    int4* d2 = (int4*)lw2;
#pragma unroll
    for (int i = 0; i < 2; ++i) {
      int c = tid + i * 1024;
      d1[c] = g[c];
      d2[c] = g[2048 + c];
    }
  }
  if (tid < 128) {
    lep[0][tid] = b1[tid];
    lep[1][tid] = W1[128 * 128 + tid];
    lep[2][tid] = W1[129 * 128 + tid];
    lep[3][tid] = W1[130 * 128 + tid];
    lep[4][tid] = b2[tid];
  }
  __syncthreads();   // the ONLY barrier

  const int wv = tid >> 6, lane = tid & 63;
  const int l15 = lane & 15, l4 = lane >> 4;
  u16* lt = lhj + wv * (16 * 128);

  const int gwid = blockIdx.x * NWAVE + wv;

  for (int g = gwid; g < NGRP; g += TOTWAVE) {
    const int eb = g * 16;

    // ---- gather 16 rows of H[src] into the wave-private swizzled tile ----
    if (BF16H) {
#pragma unroll
      for (int j = 0; j < 4; ++j) {
        int row = j * 4 + l4;
        int s = ei[eb + row];
        int boff = (l15 * 16) ^ ((row & 7) << 4);     // pre-swizzled source offset
        const char* src = (const char*)(Hb + (long)s * 128) + boff;
        __builtin_amdgcn_global_load_lds(
            (const __attribute__((address_space(1))) unsigned*)src,
            (__attribute__((address_space(3))) unsigned*)(lt + j * 4 * 128),
            16, 0, 0);
      }
      asm volatile("s_waitcnt vmcnt(0)" ::: "memory");
    } else {
#pragma unroll
      for (int j = 0; j < 4; ++j) {
        int row = j * 4 + l4;
        int s = ei[eb + row];
        const float* sp = H + (long)s * 128 + l15 * 8;
        float4 a = *(const float4*)sp;
        float4 c = *(const float4*)(sp + 4);
        int4 pk;
        pk.x = f2bf(a.x) | ((int)f2bf(a.y) << 16);
        pk.y = f2bf(a.z) | ((int)f2bf(a.w) << 16);
        pk.z = f2bf(c.x) | ((int)f2bf(c.y) << 16);
        pk.w = f2bf(c.z) | ((int)f2bf(c.w) << 16);
        *(int4*)&lt[swz(row, l15 * 8)] = pk;
      }
    }

    // ---- B fragments: Hj rows (wave-private) ----
    bf16x8 bfr[4];
#pragma unroll
    for (int ks = 0; ks < 4; ++ks)
      bfr[ks] = *(const bf16x8*)&lt[swz(l15, ks * 32 + l4 * 8)];

    int e = eb + l15;
    float ea0 = ea[e * 3 + 0], ea1 = ea[e * 3 + 1], ea2 = ea[e * 3 + 2];

    // ---- layer 1 (transposed): D[n][e], epilogue GELU, h -> same tile ----
#pragma unroll
    for (int nt = 0; nt < 8; ++nt) {
      bf16x8 afr[4];
#pragma unroll
      for (int ks = 0; ks < 4; ++ks)
        afr[ks] = *(const bf16x8*)&lw1[swz(nt * 16 + l15, ks * 32 + l4 * 8)];
      f32x4 acc = (f32x4){0.f, 0.f, 0.f, 0.f};
#pragma unroll
      for (int ks = 0; ks < 4; ++ks)
        acc = __builtin_amdgcn_mfma_f32_16x16x32_bf16(afr[ks], bfr[ks], acc, 0, 0, 0);

      f32x4 b1v = *(const f32x4*)&lep[0][nt * 16 + l4 * 4];
      f32x4 w0v = *(const f32x4*)&lep[1][nt * 16 + l4 * 4];
      f32x4 w1v = *(const f32x4*)&lep[2][nt * 16 + l4 * 4];
      f32x4 w2v = *(const f32x4*)&lep[3][nt * 16 + l4 * 4];
      float hv[4];
#pragma unroll
      for (int r = 0; r < 4; ++r) {
        float v = acc[r] + b1v[r] + ea0 * w0v[r] + ea1 * w1v[r] + ea2 * w2v[r];
        hv[r] = gelu(v);
      }
      int2 hp;
      hp.x = f2bf(hv[0]) | ((int)f2bf(hv[1]) << 16);
      hp.y = f2bf(hv[2]) | ((int)f2bf(hv[3]) << 16);
      *(int2*)&lt[swz(l15, nt * 16 + l4 * 4)] = hp;   // overwrite own row (in-order DS)
    }

    asm volatile("" ::: "memory");   // keep compiler from reordering ha reads above h writes

    // ---- layer 2: D[e][n2], coalesced 64B atomic rows ----
    bf16x8 ha[4];
#pragma unroll
    for (int ks = 0; ks < 4; ++ks)
      ha[ks] = *(const bf16x8*)&lt[swz(l15, ks * 32 + l4 * 8)];

    int drow[4];
#pragma unroll
    for (int r = 0; r < 4; ++r)
      drow[r] = ei[NEDGE + eb + l4 * 4 + r];

#pragma unroll
    for (int nt = 0; nt < 8; ++nt) {
      bf16x8 bfr2[4];
#pragma unroll
      for (int ks = 0; ks < 4; ++ks)
        bfr2[ks] = *(const bf16x8*)&lw2[swz(nt * 16 + l15, ks * 32 + l4 * 8)];
      float b2v = lep[4][nt * 16 + l15];
      f32x4 acc = (f32x4){0.f, 0.f, 0.f, 0.f};
#pragma unroll
      for (int ks = 0; ks < 4; ++ks)
        acc = __builtin_amdgcn_mfma_f32_16x16x32_bf16(ha[ks], bfr2[ks], acc, 0, 0, 0);
#pragma unroll
      for (int r = 0; r < 4; ++r)
        atomAddF32(out + (long)drow[r] * 128 + nt * 16 + l15, acc[r] + b2v);
    }
  }
}

__global__ void ln_rows(float* __restrict__ out, const float* __restrict__ gamma,
                        const float* __restrict__ beta) {
  int wave = threadIdx.x >> 6, lane = threadIdx.x & 63;
  int row = blockIdx.x * 4 + wave;
  float2 v = *(const float2*)(out + (long)row * 128 + lane * 2);
  float s = v.x + v.y;
#pragma unroll
  for (int off = 32; off; off >>= 1) s += __shfl_xor(s, off);
  float mu = s * (1.0f / 128.0f);
  float dx = v.x - mu, dy = v.y - mu;
  float q = dx * dx + dy * dy;
#pragma unroll
  for (int off = 32; off; off >>= 1) q += __shfl_xor(q, off);
  float rs = rsqrtf(q * (1.0f / 128.0f) + 1e-5f);
  float2 g = *(const float2*)(gamma + lane * 2);
  float2 b = *(const float2*)(beta + lane * 2);
  float2 o;
  o.x = dx * rs * g.x + b.x;
  o.y = dy * rs * g.y + b.y;
  *(float2*)(out + (long)row * 128 + lane * 2) = o;
}

extern "C" void kernel_launch(void* const* d_in, const int* in_sizes, int n_in,
                              void* d_out, int out_size, void* d_ws, size_t ws_size,
                              hipStream_t stream) {
  const float* H   = (const float*)d_in[0];
  const int* ei    = (const int*)d_in[1];
  const float* ea  = (const float*)d_in[2];
  const float* W1  = (const float*)d_in[3];
  const float* b1  = (const float*)d_in[4];
  const float* W2  = (const float*)d_in[5];
  const float* b2  = (const float*)d_in[6];
  const float* gam = (const float*)d_in[7];
  const float* bet = (const float*)d_in[8];
  float* out = (float*)d_out;
  u16* wsw = (u16*)d_ws;
  u16* Hb  = (u16*)((char*)d_ws + 65536);

  const size_t need = 65536 + (size_t)NT * 128 * 2;
  const bool bf16h = ws_size >= need;

  prep_w<<<128, 256, 0, stream>>>(W1, W2, wsw);
  if (bf16h) prep_h<<<3125, 256, 0, stream>>>(H, Hb);
  copy_h<<<6250, 256, 0, stream>>>((const float4*)H, (float4*)out);
  if (bf16h)
    msg_kernel<1><<<GRID, 1024, 0, stream>>>(H, Hb, ei, ea, W1, b1, b2, wsw, out);
  else
    msg_kernel<0><<<GRID, 1024, 0, stream>>>(H, Hb, ei, ea, W1, b1, b2, wsw, out);
  ln_rows<<<12500, 256, 0, stream>>>(out, gam, bet);
}